// Round 7
// baseline (657.023 us; speedup 1.0000x reference)
//
#include <hip/hip_runtime.h>
#include <hip/hip_bf16.h>
#include <math.h>

#define NGRAPHS 256
#define BSHIFT 8
#define NBUCK 512    // 256-node buckets; covers N up to 131072
#define NSORT 256    // chunks for bhist/bscatter
#define GCHUNK 1024
#define SMASK 0x00FFFFFFu  // low 24 bits = src (N < 2^24)

__device__ __forceinline__ float bf2f(unsigned short u) {
    return __uint_as_float((unsigned)u << 16);
}
__device__ __forceinline__ unsigned short f2bf(float f) {
    unsigned u = __float_as_uint(f);
    unsigned r = (u + 0x7FFFu + ((u >> 16) & 1u)) >> 16;  // RNE
    return (unsigned short)r;
}

// ---------------- dispatch 1: bucket histogram (blocks 0..255) || zero gs/pooled + L1 rel matmul (blocks 256+) ----
__global__ __launch_bounds__(256) void k_bhist(const int* __restrict__ dst, int* __restrict__ hmat, int E,
                                               const float* __restrict__ x, const float* __restrict__ w_rel1,
                                               unsigned short* __restrict__ y1b,
                                               float* __restrict__ zbase, int zwords, int N) {
    int bid = blockIdx.x, tid = threadIdx.x;
    if (bid < NSORT) {
        __shared__ int hist[NBUCK];
        for (int i = tid; i < NBUCK; i += 256) hist[i] = 0;
        __syncthreads();
        int chunk = (E + NSORT - 1) / NSORT;
        int lo = bid * chunk;
        int hi = lo + chunk; if (hi > E) hi = E;
        for (int i = lo + tid; i < hi; i += 256)
            atomicAdd(&hist[__builtin_nontemporal_load(dst + i) >> BSHIFT], 1);
        __syncthreads();
        for (int i = tid; i < NBUCK; i += 256)
            hmat[(size_t)bid * NBUCK + i] = hist[i];  // coalesced dump
    } else {
        if (bid == NSORT) {  // zero pooled/cntg + gs accumulators (re-zeroed every launch/replay)
            for (int i = tid; i < zwords; i += 256) zbase[i] = 0.f;
        }
        __shared__ float s_rel[64 * 16];
        for (int i = tid; i < 64 * 16; i += 256) s_rel[i] = w_rel1[i];
        __syncthreads();
        int total = N * 4;
        int nb = gridDim.x - NSORT;
        for (int i = (bid - NSORT) * 256 + tid; i < total; i += nb * 256) {
            int n = i >> 2, c0 = (i & 3) << 2;
            const float4* mp = (const float4*)(x + (size_t)n * 64);
            float4 acc; acc.x = 0.f; acc.y = 0.f; acc.z = 0.f; acc.w = 0.f;
#pragma unroll
            for (int k2 = 0; k2 < 16; k2++) {
                float4 v = mp[k2];
                const float* wr = &s_rel[(k2 * 4) * 16 + c0];
                float4 w0 = *(const float4*)(wr);
                float4 w1 = *(const float4*)(wr + 16);
                float4 w2 = *(const float4*)(wr + 32);
                float4 w3 = *(const float4*)(wr + 48);
                acc.x += v.x * w0.x + v.y * w1.x + v.z * w2.x + v.w * w3.x;
                acc.y += v.x * w0.y + v.y * w1.y + v.z * w2.y + v.w * w3.y;
                acc.z += v.x * w0.z + v.y * w1.z + v.z * w2.z + v.w * w3.z;
                acc.w += v.x * w0.w + v.y * w1.w + v.z * w2.w + v.w * w3.w;
            }
            ushort4 o; o.x = f2bf(acc.x); o.y = f2bf(acc.y); o.z = f2bf(acc.z); o.w = f2bf(acc.w);
            *(ushort4*)(y1b + (size_t)n * 16 + c0) = o;
        }
    }
}

// ---------------- dispatch 2: merged column scan + bucket scan (one block, 512 threads) ----------------
__global__ __launch_bounds__(512) void k_scan(int* __restrict__ hmat, int* __restrict__ bstart) {
    __shared__ int s[512];
    int col = threadIdx.x;
    int run = 0;
#pragma unroll 4
    for (int r = 0; r < NSORT; r++) {
        int v = hmat[(size_t)r * NBUCK + col];
        hmat[(size_t)r * NBUCK + col] = run;
        run += v;
    }
    s[col] = run;
    __syncthreads();
    for (int off = 1; off < 512; off <<= 1) {
        int t = (col >= off) ? s[col - off] : 0;
        __syncthreads();
        s[col] += t;
        __syncthreads();
    }
    bstart[col] = s[col] - run;  // exclusive
    if (col == 511) bstart[NBUCK] = s[511];
}

// ---------------- dispatch 3: scatter into bucket-ordered ebuf ----------------
__global__ __launch_bounds__(256) void k_bscatter(const int* __restrict__ src, const int* __restrict__ dst,
                                                  const int* __restrict__ hmat, const int* __restrict__ bstart,
                                                  unsigned* __restrict__ ebuf, int E) {
    __shared__ int cur[NBUCK];
    for (int i = threadIdx.x; i < NBUCK; i += 256)
        cur[i] = bstart[i] + hmat[(size_t)blockIdx.x * NBUCK + i];
    __syncthreads();
    int chunk = (E + NSORT - 1) / NSORT;
    int lo = blockIdx.x * chunk;
    int hi = lo + chunk; if (hi > E) hi = E;
    for (int i = lo + threadIdx.x; i < hi; i += 256) {
        int d = __builtin_nontemporal_load(dst + i);
        int s = __builtin_nontemporal_load(src + i);
        int p = atomicAdd(&cur[d >> BSHIFT], 1);
        ebuf[p] = (unsigned)s | ((unsigned)(d & 255) << 24);
    }
}

// ---------------- dispatch 4: per-bucket LDS counting sort -> full CSR + row_start ----------------
__global__ __launch_bounds__(256) void k_sort2(const unsigned* __restrict__ ebuf, const int* __restrict__ bstart,
                                               int* __restrict__ csr, int* __restrict__ row_start, int N) {
    __shared__ int hist[256];
    __shared__ int sc[256];
    __shared__ int scur[256];
    int b = blockIdx.x;
    int e0 = bstart[b], e1 = bstart[b + 1];
    hist[threadIdx.x] = 0;
    __syncthreads();
    for (int i = e0 + threadIdx.x; i < e1; i += 256)
        atomicAdd(&hist[__builtin_nontemporal_load(ebuf + i) >> 24], 1);
    __syncthreads();
    sc[threadIdx.x] = hist[threadIdx.x];
    __syncthreads();
    for (int off = 1; off < 256; off <<= 1) {
        int t = (threadIdx.x >= off) ? sc[threadIdx.x - off] : 0;
        __syncthreads();
        sc[threadIdx.x] += t;
        __syncthreads();
    }
    {
        int inc = sc[threadIdx.x];
        int ex = inc - hist[threadIdx.x];
        scur[threadIdx.x] = e0 + ex;
        int node = (b << BSHIFT) + threadIdx.x;
        if (node < N) row_start[node] = e0 + ex;
        if (node == N - 1) row_start[N] = e0 + inc;  // == E
    }
    __syncthreads();
    for (int i = e0 + threadIdx.x; i < e1; i += 256) {
        unsigned w = __builtin_nontemporal_load(ebuf + i);
        int p = atomicAdd(&scur[w >> 24], 1);
        csr[p] = (int)(w & SMASK);
    }
}

// ---------------- gather: LDS-staged csr + fully-predicated clamp batches (4 loads in flight) ----------------
template <int C>
__global__ __launch_bounds__(256) void k_gather(const unsigned short* __restrict__ h,
                                                const int* __restrict__ row_start,
                                                const int* __restrict__ csr, float* __restrict__ agg, int N) {
    constexpr int LPR = C / 4;       // lanes per edge-line
    constexpr int EPP = 64 / LPR;    // edge slots per wave instruction
    constexpr int BATCH = 4 * EPP;   // 4 loads in flight per batch
    __shared__ int sbuf[GCHUNK];
    int lane = threadIdx.x & 63;
    int w = threadIdx.x >> 6;
    int nb = blockIdx.x * 4;
    int wid = nb + w;
    bool act = wid < N;
    int nb_end = nb + 4; if (nb_end > N) nb_end = N;
    int eb0 = row_start[nb];
    int eb1 = row_start[nb_end];
    int r0 = act ? row_start[wid] : 0;
    int r1 = act ? row_start[wid + 1] : 0;
    int es = lane / LPR;
    int cq = (lane % LPR) * 4;

    float a0 = 0.f, a1 = 0.f, a2 = 0.f, a3 = 0.f;
    for (int base = eb0; base < eb1; base += GCHUNK) {
        int len = eb1 - base; if (len > GCHUNK) len = GCHUNK;
        __syncthreads();
        for (int i = threadIdx.x; i < len; i += 256)
            sbuf[i] = __builtin_nontemporal_load(csr + base + i);
        __syncthreads();
        if (act) {
            int lo = (r0 > base ? r0 : base) - base;
            int hiv = r1 < base + len ? r1 : base + len;
            int hi = hiv - base;
            for (int j0 = lo; j0 < hi; j0 += BATCH) {
                int s[4]; bool p[4];
#pragma unroll
                for (int u = 0; u < 4; u++) {
                    int j = j0 + u * EPP + es;
                    p[u] = j < hi;
                    s[u] = sbuf[p[u] ? j : j0];  // clamp to batch base: duplicated hot line, no serial path
                }
                ushort4 v[4];
#pragma unroll
                for (int u = 0; u < 4; u++)
                    v[u] = *(const ushort4*)(h + (size_t)s[u] * C + cq);
#pragma unroll
                for (int u = 0; u < 4; u++) {
                    if (p[u]) {
                        a0 += bf2f(v[u].x); a1 += bf2f(v[u].y);
                        a2 += bf2f(v[u].z); a3 += bf2f(v[u].w);
                    }
                }
            }
        }
    }
#pragma unroll
    for (int off = LPR; off < 64; off <<= 1) {
        a0 += __shfl_xor(a0, off, 64);
        a1 += __shfl_xor(a1, off, 64);
        a2 += __shfl_xor(a2, off, 64);
        a3 += __shfl_xor(a3, off, 64);
    }
    if (act && lane < LPR) {
        int deg = r1 - r0;
        float rec = 1.0f / (float)(deg > 0 ? deg : 1);
        float4 o; o.x = a0 * rec; o.y = a1 * rec; o.z = a2 * rec; o.w = a3 * rec;
        *(float4*)(agg + (size_t)wid * C + cq) = o;
    }
}

// ---------------- dense layer + BN-stat sums; 4 nodes per thread to amortize LDS weight reads 4x ---------------
// Thread (g,q) computes nodes 4g..4g+3 at channel quad q: per cb, 8 ds_read_b128 serve 4 nodes (was 1).
template <int CI, int CO, bool HAS_REL, bool ADD_AGG, bool IN_BF16>
__global__ __launch_bounds__(256) void k_lin_stats(const void* __restrict__ hroot_v, const float* __restrict__ hrel,
                                                   const float* __restrict__ w_rel, const float* __restrict__ w_root,
                                                   const float* __restrict__ bias,
                                                   float* __restrict__ out, float* __restrict__ gsl, int N) {
    constexpr int QPR = CO / 4;
    __shared__ float s_rel[HAS_REL ? CI * CO : 1];
    __shared__ float s_root[CI * CO];
    __shared__ float s_b[CO];
    __shared__ float part[4][2 * CO];
    int tid = threadIdx.x;
    if (HAS_REL)
        for (int i = tid; i < CI * CO; i += 256) s_rel[i] = w_rel[i];
    for (int i = tid; i < CI * CO; i += 256) s_root[i] = w_root[i];
    if (tid < CO) s_b[tid] = bias[tid];
    __syncthreads();

    int ngrp = (N + 3) >> 2;
    int total = ngrp * QPR;
    int stride = gridDim.x * 256;  // 256 % QPR == 0 -> q constant per thread
    float s0 = 0, s1 = 0, s2 = 0, s3 = 0, q0 = 0, q1 = 0, q2 = 0, q3 = 0;
    for (int i = blockIdx.x * 256 + tid; i < total; i += stride) {
        int g4 = i / QPR, q = i % QPR, c0 = q * 4;
        int n0 = g4 * 4;
        int nm = N - n0; if (nm > 4) nm = 4;  // tail guard (N%4) — uniform for all but last group
        float4 bias4 = *(const float4*)&s_b[c0];
        float4 acc[4];
#pragma unroll
        for (int m = 0; m < 4; m++) acc[m] = bias4;
        if (ADD_AGG) {
#pragma unroll
            for (int m = 0; m < 4; m++)
                if (m < nm) {
                    float4 v = ((const float4*)hrel)[(size_t)(n0 + m) * QPR + q];
                    acc[m].x += v.x; acc[m].y += v.y; acc[m].z += v.z; acc[m].w += v.w;
                }
        }
#pragma unroll
        for (int cb = 0; cb < CI / 4; cb++) {
            const float* wr = &s_root[(cb * 4) * CO + c0];
            float4 w0 = *(const float4*)(wr);
            float4 w1 = *(const float4*)(wr + CO);
            float4 w2 = *(const float4*)(wr + 2 * CO);
            float4 w3 = *(const float4*)(wr + 3 * CO);
            float4 e0, e1, e2, e3;
            if (HAS_REL) {
                const float* we = &s_rel[(cb * 4) * CO + c0];
                e0 = *(const float4*)(we);
                e1 = *(const float4*)(we + CO);
                e2 = *(const float4*)(we + 2 * CO);
                e3 = *(const float4*)(we + 3 * CO);
            }
#pragma unroll
            for (int m = 0; m < 4; m++) {
                if (m < nm) {
                    float f0, f1, f2, f3;
                    if (IN_BF16) {
                        ushort4 v = *(const ushort4*)((const unsigned short*)hroot_v + (size_t)(n0 + m) * CI + cb * 4);
                        f0 = bf2f(v.x); f1 = bf2f(v.y); f2 = bf2f(v.z); f3 = bf2f(v.w);
                    } else {
                        float4 v = *(const float4*)((const float*)hroot_v + (size_t)(n0 + m) * CI + cb * 4);
                        f0 = v.x; f1 = v.y; f2 = v.z; f3 = v.w;
                    }
                    acc[m].x += f0 * w0.x + f1 * w1.x + f2 * w2.x + f3 * w3.x;
                    acc[m].y += f0 * w0.y + f1 * w1.y + f2 * w2.y + f3 * w3.y;
                    acc[m].z += f0 * w0.z + f1 * w1.z + f2 * w2.z + f3 * w3.z;
                    acc[m].w += f0 * w0.w + f1 * w1.w + f2 * w2.w + f3 * w3.w;
                    if (HAS_REL) {
                        float4 a = *(const float4*)(hrel + (size_t)(n0 + m) * CI + cb * 4);
                        acc[m].x += a.x * e0.x + a.y * e1.x + a.z * e2.x + a.w * e3.x;
                        acc[m].y += a.x * e0.y + a.y * e1.y + a.z * e2.y + a.w * e3.y;
                        acc[m].z += a.x * e0.z + a.y * e1.z + a.z * e2.z + a.w * e3.z;
                        acc[m].w += a.x * e0.w + a.y * e1.w + a.z * e2.w + a.w * e3.w;
                    }
                }
            }
        }
#pragma unroll
        for (int m = 0; m < 4; m++) {
            if (m < nm) {
                ((float4*)out)[(size_t)(n0 + m) * QPR + q] = acc[m];
                s0 += acc[m].x; q0 += acc[m].x * acc[m].x;
                s1 += acc[m].y; q1 += acc[m].y * acc[m].y;
                s2 += acc[m].z; q2 += acc[m].z * acc[m].z;
                s3 += acc[m].w; q3 += acc[m].w * acc[m].w;
            }
        }
    }
#pragma unroll
    for (int off = QPR; off < 64; off <<= 1) {
        s0 += __shfl_xor(s0, off, 64); q0 += __shfl_xor(q0, off, 64);
        s1 += __shfl_xor(s1, off, 64); q1 += __shfl_xor(q1, off, 64);
        s2 += __shfl_xor(s2, off, 64); q2 += __shfl_xor(q2, off, 64);
        s3 += __shfl_xor(s3, off, 64); q3 += __shfl_xor(q3, off, 64);
    }
    int lane = tid & 63;
    int w = tid >> 6;
    if (lane < QPR) {
        int cq = lane * 4;
        part[w][cq + 0] = s0; part[w][CO + cq + 0] = q0;
        part[w][cq + 1] = s1; part[w][CO + cq + 1] = q1;
        part[w][cq + 2] = s2; part[w][CO + cq + 2] = q2;
        part[w][cq + 3] = s3; part[w][CO + cq + 3] = q3;
    }
    __syncthreads();
    if (tid < 2 * CO) {
        float v = part[0][tid] + part[1][tid] + part[2][tid] + part[3][tid];
        atomicAdd(&gsl[tid], v);  // 128 addresses; ordering to consumer = next kernel boundary
    }
}

// ---------------- BN apply + ELU: scale/shift from finished gs sums; write bf16 (layers 1-3) ----------------
template <int CO>
__global__ __launch_bounds__(256) void k_bn_elu(const float* __restrict__ h, const float* __restrict__ gsl,
                                                const float* __restrict__ g, const float* __restrict__ be,
                                                unsigned short* __restrict__ hb, float invN, int N) {
    __shared__ float sc[CO], sh[CO];
    if (threadIdx.x < CO) {
        int c = threadIdx.x;
        float mean = gsl[c] * invN;
        float var = gsl[CO + c] * invN - mean * mean;
        float s = g[c] * rsqrtf(var + 1e-5f);
        sc[c] = s;
        sh[c] = be[c] - mean * s;
    }
    __syncthreads();
    int total = N * (CO / 4);
    int i = blockIdx.x * 256 + threadIdx.x;
    if (i >= total) return;
    float4 v = ((const float4*)h)[i];
    int cq = (i % (CO / 4)) * 4;
    v.x = v.x * sc[cq + 0] + sh[cq + 0];
    v.y = v.y * sc[cq + 1] + sh[cq + 1];
    v.z = v.z * sc[cq + 2] + sh[cq + 2];
    v.w = v.w * sc[cq + 3] + sh[cq + 3];
    v.x = v.x > 0.f ? v.x : expm1f(v.x);
    v.y = v.y > 0.f ? v.y : expm1f(v.y);
    v.z = v.z > 0.f ? v.z : expm1f(v.z);
    v.w = v.w > 0.f ? v.w : expm1f(v.w);
    ushort4 o;
    o.x = f2bf(v.x); o.y = f2bf(v.y); o.z = f2bf(v.z); o.w = f2bf(v.w);
    ((ushort4*)hb)[i] = o;
}

// ---------------- layer 4: BN + ELU + global mean pool fused (16 nodes/wave, fp32, no fences) ----------------
__global__ __launch_bounds__(256) void k_bn_elu_pool(const float* __restrict__ h, const float* __restrict__ gsl,
                                                     const float* __restrict__ g, const float* __restrict__ be,
                                                     const int* __restrict__ batch,
                                                     float* __restrict__ pooled, float* __restrict__ cntg,
                                                     float invN, int N) {
    __shared__ float sc[64], sh[64];
    if (threadIdx.x < 64) {
        int c = threadIdx.x;
        float mean = gsl[c] * invN;
        float var = gsl[64 + c] * invN - mean * mean;
        float s = g[c] * rsqrtf(var + 1e-5f);
        sc[c] = s;
        sh[c] = be[c] - mean * s;
    }
    __syncthreads();
    int lane = threadIdx.x & 63;  // lane == channel
    int wid = blockIdx.x * 4 + (threadIdx.x >> 6);
    int n0 = wid * 16;
    if (n0 >= N) return;
    float scl = sc[lane];
    float shl = sh[lane];
    int nmax = N - n0; if (nmax > 16) nmax = 16;
    int cur = batch[n0];
    float acc = 0.f;
    float run = 0.f;
    for (int k = 0; k < nmax; k++) {
        int gg = batch[n0 + k];
        if (gg != cur) {
            atomicAdd(&pooled[(size_t)cur * 64 + lane], acc);
            if (lane == 0) atomicAdd(&cntg[cur], run);
            cur = gg; acc = 0.f; run = 0.f;
        }
        float v = h[(size_t)(n0 + k) * 64 + lane] * scl + shl;
        v = v > 0.f ? v : expm1f(v);
        acc += v;
        run += 1.f;
    }
    atomicAdd(&pooled[(size_t)cur * 64 + lane], acc);
    if (lane == 0) atomicAdd(&cntg[cur], run);
}

// ---------------- head ----------------
__global__ __launch_bounds__(256) void k_head(const float* __restrict__ pooled, const float* __restrict__ cntg,
                                              const float* __restrict__ w1, const float* __restrict__ b1,
                                              const float* __restrict__ w2, const float* __restrict__ b2,
                                              float* __restrict__ out) {
    int g = threadIdx.x;  // 256 threads == 256 graphs
    float rec = 1.0f / fmaxf(cntg[g], 1.0f);
    float p[64];
    {
        const float4* pp = (const float4*)(pooled + (size_t)g * 64);
#pragma unroll
        for (int i = 0; i < 16; i++) {
            float4 v = pp[i];
            p[4 * i + 0] = v.x * rec; p[4 * i + 1] = v.y * rec;
            p[4 * i + 2] = v.z * rec; p[4 * i + 3] = v.w * rec;
        }
    }
    float lg[10];
#pragma unroll
    for (int t = 0; t < 10; t++) lg[t] = b2[t];
#pragma unroll 1
    for (int j = 0; j < 64; j++) {
        float a = b1[j];
#pragma unroll
        for (int k = 0; k < 64; k++) a += p[k] * w1[k * 64 + j];  // uniform -> s_load
        a = fmaxf(a, 0.f);
#pragma unroll
        for (int t = 0; t < 10; t++) lg[t] += a * w2[j * 10 + t];
    }
    float m = -1e30f;
#pragma unroll
    for (int t = 0; t < 10; t++) m = fmaxf(m, lg[t]);
    float s = 0.f;
#pragma unroll
    for (int t = 0; t < 10; t++) s += expf(lg[t] - m);
    float lse = m + logf(s);
#pragma unroll
    for (int t = 0; t < 10; t++) out[(size_t)g * 10 + t] = lg[t] - lse;
}

extern "C" void kernel_launch(void* const* d_in, const int* in_sizes, int n_in,
                              void* d_out, int out_size, void* d_ws, size_t ws_size,
                              hipStream_t stream) {
    const float* x = (const float*)d_in[0];
    const int* ei = (const int*)d_in[1];
    const int* batch = (const int*)d_in[2];
    const int N = in_sizes[0] / 64;
    const int E = in_sizes[1] / 2;
    const int* src = ei;
    const int* dst = ei + E;

    const float* w_rel1 = (const float*)d_in[3];
    const float* w_root1 = (const float*)d_in[4];
    const float* b1 = (const float*)d_in[5];
    const float* g1 = (const float*)d_in[6];
    const float* be1 = (const float*)d_in[7];
    const float* w_rel2 = (const float*)d_in[8];
    const float* w_root2 = (const float*)d_in[9];
    const float* b2 = (const float*)d_in[10];
    const float* g2 = (const float*)d_in[11];
    const float* be2 = (const float*)d_in[12];
    const float* w_rel3 = (const float*)d_in[13];
    const float* w_root3 = (const float*)d_in[14];
    const float* b3 = (const float*)d_in[15];
    const float* g3 = (const float*)d_in[16];
    const float* be3 = (const float*)d_in[17];
    const float* w_rel4 = (const float*)d_in[18];
    const float* w_root4 = (const float*)d_in[19];
    const float* b4 = (const float*)d_in[20];
    const float* g4 = (const float*)d_in[21];
    const float* be4 = (const float*)d_in[22];
    const float* w_lin1 = (const float*)d_in[23];
    const float* b_lin1 = (const float*)d_in[24];
    const float* w_lin2 = (const float*)d_in[25];
    const float* b_lin2 = (const float*)d_in[26];

    char* ws = (char*)d_ws;
    size_t off = 0;
    auto alloc = [&](size_t bytes) { size_t o = off; off += (bytes + 255) & ~(size_t)255; return o; };
    int* hmat = (int*)(ws + alloc((size_t)NSORT * NBUCK * 4));
    int* bstart = (int*)(ws + alloc((size_t)(NBUCK + 1) * 4));
    unsigned* ebuf = (unsigned*)(ws + alloc((size_t)E * 4));
    int* csr = (int*)(ws + alloc((size_t)E * 4));
    int* row_start = (int*)(ws + alloc((size_t)(N + 1) * 4));
    float* agg = (float*)(ws + alloc((size_t)N * 32 * 4));
    unsigned short* y1b = (unsigned short*)(ws + alloc((size_t)N * 16 * 2));
    unsigned short* hb = (unsigned short*)(ws + alloc((size_t)N * 64 * 2));
    float* bufA = (float*)(ws + alloc((size_t)N * 64 * 4));
    // zero region: gs (4 layers x 128) + pooled + cntg, contiguous
    float* gs = (float*)(ws + alloc((size_t)(512 + NGRAPHS * 64 + NGRAPHS) * 4));
    float* pooled = gs + 512;
    float* cntg = pooled + NGRAPHS * 64;
    const int zwords = 512 + NGRAPHS * 64 + NGRAPHS;

    const float invN = 1.0f / (float)N;
    const int gbl = (N + 3) / 4;       // gather: 4 waves/block, 1 wave/node
    const int ngrp = (N + 3) / 4;      // lin_stats: 4 nodes/thread
    auto lsgrid = [&](int qpr) { return (ngrp * qpr + 255) / 256; };

    // ---- CSR build; dispatch 1 also zeroes gs/pooled and runs L1 rel matmul in disjoint blocks ----
    k_bhist<<<1024, 256, 0, stream>>>(dst, hmat, E, x, w_rel1, y1b, gs, zwords, N);
    k_scan<<<1, 512, 0, stream>>>(hmat, bstart);
    k_bscatter<<<NSORT, 256, 0, stream>>>(src, dst, hmat, bstart, ebuf, E);
    k_sort2<<<NBUCK, 256, 0, stream>>>(ebuf, bstart, csr, row_start, N);

    // ---- Layer 1 (64 -> 16) ----
    k_gather<16><<<gbl, 256, 0, stream>>>(y1b, row_start, csr, agg, N);
    k_lin_stats<64, 16, false, true, false><<<lsgrid(4), 256, 0, stream>>>(
        x, agg, nullptr, w_root1, b1, bufA, gs + 0, N);
    k_bn_elu<16><<<(N * 4 + 255) / 256, 256, 0, stream>>>(bufA, gs + 0, g1, be1, hb, invN, N);

    // ---- Layer 2 (16 -> 32) ----
    k_gather<16><<<gbl, 256, 0, stream>>>(hb, row_start, csr, agg, N);
    k_lin_stats<16, 32, true, false, true><<<lsgrid(8), 256, 0, stream>>>(
        hb, agg, w_rel2, w_root2, b2, bufA, gs + 128, N);
    k_bn_elu<32><<<(N * 8 + 255) / 256, 256, 0, stream>>>(bufA, gs + 128, g2, be2, hb, invN, N);

    // ---- Layer 3 (32 -> 32) ----
    k_gather<32><<<gbl, 256, 0, stream>>>(hb, row_start, csr, agg, N);
    k_lin_stats<32, 32, true, false, true><<<lsgrid(8), 256, 0, stream>>>(
        hb, agg, w_rel3, w_root3, b3, bufA, gs + 256, N);
    k_bn_elu<32><<<(N * 8 + 255) / 256, 256, 0, stream>>>(bufA, gs + 256, g3, be3, hb, invN, N);

    // ---- Layer 4 (32 -> 64): lin+stats, then fused BN+ELU+pool ----
    k_gather<32><<<gbl, 256, 0, stream>>>(hb, row_start, csr, agg, N);
    k_lin_stats<32, 64, true, false, true><<<lsgrid(16), 256, 0, stream>>>(
        hb, agg, w_rel4, w_root4, b4, bufA, gs + 384, N);
    int waves16 = (N + 15) / 16;
    k_bn_elu_pool<<<(waves16 + 3) / 4, 256, 0, stream>>>(
        bufA, gs + 384, g4, be4, batch, pooled, cntg, invN, N);

    // ---- head ----
    k_head<<<1, 256, 0, stream>>>(pooled, cntg, w_lin1, b_lin1, w_lin2, b_lin2, (float*)d_out);
}

// Round 8
// 609.309 us; speedup vs baseline: 1.0783x; 1.0783x over previous
//
#include <hip/hip_runtime.h>
#include <hip/hip_bf16.h>
#include <math.h>

#define NGRAPHS 256
#define BSHIFT 8
#define NBUCK 512    // 256-node buckets; covers N up to 131072
#define NSORT 256    // chunks for bhist/bscatter
#define GCHUNK 1024
#define SMASK 0x00FFFFFFu  // low 24 bits = src (N < 2^24)

__device__ __forceinline__ float bf2f(unsigned short u) {
    return __uint_as_float((unsigned)u << 16);
}
__device__ __forceinline__ unsigned short f2bf(float f) {
    unsigned u = __float_as_uint(f);
    unsigned r = (u + 0x7FFFu + ((u >> 16) & 1u)) >> 16;  // RNE
    return (unsigned short)r;
}

// ---------------- dispatch 1: bucket histogram + atomic base claim (blocks 0..255) || L1 rel matmul (256+) ------
// Each hist block claims its within-bucket base via atomicAdd(colpos) — row order within a bucket is arbitrary,
// which is fine: bucket contents are re-sorted by k_sort2, and edge order within a dst row is already
// nondeterministic (LDS atomics). Kills the serial k_cscan/k_scan column walk entirely.
__global__ __launch_bounds__(256) void k_bhist(const int* __restrict__ dst, int* __restrict__ hmat, int E,
                                               const float* __restrict__ x, const float* __restrict__ w_rel1,
                                               unsigned short* __restrict__ y1b,
                                               int* __restrict__ colpos, int N) {
    int bid = blockIdx.x, tid = threadIdx.x;
    if (bid < NSORT) {
        __shared__ int hist[NBUCK];
        for (int i = tid; i < NBUCK; i += 256) hist[i] = 0;
        __syncthreads();
        int chunk = (E + NSORT - 1) / NSORT;
        int lo = bid * chunk;
        int hi = lo + chunk; if (hi > E) hi = E;
        for (int i = lo + tid; i < hi; i += 256)
            atomicAdd(&hist[__builtin_nontemporal_load(dst + i) >> BSHIFT], 1);
        __syncthreads();
        for (int i = tid; i < NBUCK; i += 256) {
            int h = hist[i];
            int base = atomicAdd(&colpos[i], h);  // claim [base, base+h) within bucket i
            hmat[(size_t)bid * NBUCK + i] = base;
        }
    } else {
        __shared__ float s_rel[64 * 16];
        for (int i = tid; i < 64 * 16; i += 256) s_rel[i] = w_rel1[i];
        __syncthreads();
        int total = N * 4;
        int nb = gridDim.x - NSORT;
        for (int i = (bid - NSORT) * 256 + tid; i < total; i += nb * 256) {
            int n = i >> 2, c0 = (i & 3) << 2;
            const float4* mp = (const float4*)(x + (size_t)n * 64);
            float4 acc; acc.x = 0.f; acc.y = 0.f; acc.z = 0.f; acc.w = 0.f;
#pragma unroll
            for (int k2 = 0; k2 < 16; k2++) {
                float4 v = mp[k2];
                const float* wr = &s_rel[(k2 * 4) * 16 + c0];
                float4 w0 = *(const float4*)(wr);
                float4 w1 = *(const float4*)(wr + 16);
                float4 w2 = *(const float4*)(wr + 32);
                float4 w3 = *(const float4*)(wr + 48);
                acc.x += v.x * w0.x + v.y * w1.x + v.z * w2.x + v.w * w3.x;
                acc.y += v.x * w0.y + v.y * w1.y + v.z * w2.y + v.w * w3.y;
                acc.z += v.x * w0.z + v.y * w1.z + v.z * w2.z + v.w * w3.z;
                acc.w += v.x * w0.w + v.y * w1.w + v.z * w2.w + v.w * w3.w;
            }
            ushort4 o; o.x = f2bf(acc.x); o.y = f2bf(acc.y); o.z = f2bf(acc.z); o.w = f2bf(acc.w);
            *(ushort4*)(y1b + (size_t)n * 16 + c0) = o;
        }
    }
}

// ---------------- dispatch 2: scatter into bucket-ordered ebuf; per-block redundant 512-entry bucket scan -------
__global__ __launch_bounds__(512) void k_bscatter(const int* __restrict__ src, const int* __restrict__ dst,
                                                  const int* __restrict__ hmat, const int* __restrict__ colpos,
                                                  int* __restrict__ bstart_g,
                                                  unsigned* __restrict__ ebuf, int E) {
    __shared__ int s[NBUCK];
    __shared__ int cur[NBUCK];
    int tid = threadIdx.x;
    int b = blockIdx.x;
    int v = colpos[tid];  // total count of bucket tid (post-bhist)
    s[tid] = v;
    __syncthreads();
    for (int off = 1; off < NBUCK; off <<= 1) {
        int t = (tid >= off) ? s[tid - off] : 0;
        __syncthreads();
        s[tid] += t;
        __syncthreads();
    }
    int excl = s[tid] - v;  // exclusive bucket start
    if (b == 0) {  // publish for k_sort2 (any single block works; 0 is convenient)
        bstart_g[tid] = excl;
        if (tid == NBUCK - 1) bstart_g[NBUCK] = s[NBUCK - 1];
    }
    cur[tid] = excl + hmat[(size_t)b * NBUCK + tid];
    __syncthreads();
    int chunk = (E + NSORT - 1) / NSORT;
    int lo = b * chunk;
    int hi = lo + chunk; if (hi > E) hi = E;
    for (int i = lo + tid; i < hi; i += 512) {
        int d = __builtin_nontemporal_load(dst + i);
        int sv = __builtin_nontemporal_load(src + i);
        int p = atomicAdd(&cur[d >> BSHIFT], 1);
        ebuf[p] = (unsigned)sv | ((unsigned)(d & 255) << 24);
    }
}

// ---------------- dispatch 3: per-bucket LDS counting sort -> full CSR + row_start ----------------
__global__ __launch_bounds__(256) void k_sort2(const unsigned* __restrict__ ebuf, const int* __restrict__ bstart,
                                               int* __restrict__ csr, int* __restrict__ row_start, int N) {
    __shared__ int hist[256];
    __shared__ int sc[256];
    __shared__ int scur[256];
    int b = blockIdx.x;
    int e0 = bstart[b], e1 = bstart[b + 1];
    hist[threadIdx.x] = 0;
    __syncthreads();
    for (int i = e0 + threadIdx.x; i < e1; i += 256)
        atomicAdd(&hist[__builtin_nontemporal_load(ebuf + i) >> 24], 1);
    __syncthreads();
    sc[threadIdx.x] = hist[threadIdx.x];
    __syncthreads();
    for (int off = 1; off < 256; off <<= 1) {
        int t = (threadIdx.x >= off) ? sc[threadIdx.x - off] : 0;
        __syncthreads();
        sc[threadIdx.x] += t;
        __syncthreads();
    }
    {
        int inc = sc[threadIdx.x];
        int ex = inc - hist[threadIdx.x];
        scur[threadIdx.x] = e0 + ex;
        int node = (b << BSHIFT) + threadIdx.x;
        if (node < N) row_start[node] = e0 + ex;
        if (node == N - 1) row_start[N] = e0 + inc;  // == E
    }
    __syncthreads();
    for (int i = e0 + threadIdx.x; i < e1; i += 256) {
        unsigned w = __builtin_nontemporal_load(ebuf + i);
        int p = atomicAdd(&scur[w >> 24], 1);
        csr[p] = (int)(w & SMASK);
    }
}

// ---------------- gather: LDS-staged csr + fully-predicated clamp batches (4 loads in flight) ----------------
template <int C>
__global__ __launch_bounds__(256) void k_gather(const unsigned short* __restrict__ h,
                                                const int* __restrict__ row_start,
                                                const int* __restrict__ csr, float* __restrict__ agg, int N) {
    constexpr int LPR = C / 4;       // lanes per edge-line
    constexpr int EPP = 64 / LPR;    // edge slots per wave instruction
    constexpr int BATCH = 4 * EPP;   // 4 loads in flight per batch
    __shared__ int sbuf[GCHUNK];
    int lane = threadIdx.x & 63;
    int w = threadIdx.x >> 6;
    int nb = blockIdx.x * 4;
    int wid = nb + w;
    bool act = wid < N;
    int nb_end = nb + 4; if (nb_end > N) nb_end = N;
    int eb0 = row_start[nb];
    int eb1 = row_start[nb_end];
    int r0 = act ? row_start[wid] : 0;
    int r1 = act ? row_start[wid + 1] : 0;
    int es = lane / LPR;
    int cq = (lane % LPR) * 4;

    float a0 = 0.f, a1 = 0.f, a2 = 0.f, a3 = 0.f;
    for (int base = eb0; base < eb1; base += GCHUNK) {
        int len = eb1 - base; if (len > GCHUNK) len = GCHUNK;
        __syncthreads();
        for (int i = threadIdx.x; i < len; i += 256)
            sbuf[i] = __builtin_nontemporal_load(csr + base + i);
        __syncthreads();
        if (act) {
            int lo = (r0 > base ? r0 : base) - base;
            int hiv = r1 < base + len ? r1 : base + len;
            int hi = hiv - base;
            for (int j0 = lo; j0 < hi; j0 += BATCH) {
                int s[4]; bool p[4];
#pragma unroll
                for (int u = 0; u < 4; u++) {
                    int j = j0 + u * EPP + es;
                    p[u] = j < hi;
                    s[u] = sbuf[p[u] ? j : j0];  // clamp to batch base: duplicated hot line, no serial path
                }
                ushort4 v[4];
#pragma unroll
                for (int u = 0; u < 4; u++)
                    v[u] = *(const ushort4*)(h + (size_t)s[u] * C + cq);
#pragma unroll
                for (int u = 0; u < 4; u++) {
                    if (p[u]) {
                        a0 += bf2f(v[u].x); a1 += bf2f(v[u].y);
                        a2 += bf2f(v[u].z); a3 += bf2f(v[u].w);
                    }
                }
            }
        }
    }
#pragma unroll
    for (int off = LPR; off < 64; off <<= 1) {
        a0 += __shfl_xor(a0, off, 64);
        a1 += __shfl_xor(a1, off, 64);
        a2 += __shfl_xor(a2, off, 64);
        a3 += __shfl_xor(a3, off, 64);
    }
    if (act && lane < LPR) {
        int deg = r1 - r0;
        float rec = 1.0f / (float)(deg > 0 ? deg : 1);
        float4 o; o.x = a0 * rec; o.y = a1 * rec; o.z = a2 * rec; o.w = a3 * rec;
        *(float4*)(agg + (size_t)wid * C + cq) = o;
    }
}

// ---------------- dense layer + BN-stat sums; 4 SPLIT-STREAM nodes per thread --------------------------------
// Thread (n0,q) computes nodes n0, n0+nq, n0+2nq, n0+3nq (nq = ceil(N/4)) at channel quad q.
// Weights loaded from LDS once per cb serve 4 nodes (4x fewer ds_read_b128 than 1-node/thread) while every
// stream's global reads/writes stay fully coalesced (4 independent contiguous streams) — fixes round-7's
// scattered-256B regression.
template <int CI, int CO, bool HAS_REL, bool ADD_AGG, bool IN_BF16>
__global__ __launch_bounds__(256) void k_lin_stats(const void* __restrict__ hroot_v, const float* __restrict__ hrel,
                                                   const float* __restrict__ w_rel, const float* __restrict__ w_root,
                                                   const float* __restrict__ bias,
                                                   float* __restrict__ out, float* __restrict__ gsl, int N) {
    constexpr int QPR = CO / 4;
    __shared__ float s_rel[HAS_REL ? CI * CO : 1];
    __shared__ float s_root[CI * CO];
    __shared__ float s_b[CO];
    __shared__ float part[4][2 * CO];
    int tid = threadIdx.x;
    if (HAS_REL)
        for (int i = tid; i < CI * CO; i += 256) s_rel[i] = w_rel[i];
    for (int i = tid; i < CI * CO; i += 256) s_root[i] = w_root[i];
    if (tid < CO) s_b[tid] = bias[tid];
    __syncthreads();

    int nq = (N + 3) >> 2;         // nodes per stream
    int totalq = nq * QPR;         // elements per stream
    float s0 = 0, s1 = 0, s2 = 0, s3 = 0, q0 = 0, q1 = 0, q2 = 0, q3 = 0;
    int i = blockIdx.x * 256 + tid;
    if (i < totalq) {
        int n0 = i / QPR, q = i % QPR, c0 = q * 4;
        int n1 = n0 + nq, n2 = n0 + 2 * nq, n3 = n0 + 3 * nq;
        bool v1 = n1 < N, v2 = n2 < N, v3 = n3 < N;  // wave-uniform except at one boundary
        float4 bias4 = *(const float4*)&s_b[c0];
        float4 acc0 = bias4, acc1 = bias4, acc2 = bias4, acc3 = bias4;
        if (ADD_AGG) {
            float4 v = ((const float4*)hrel)[(size_t)n0 * QPR + q];
            acc0.x += v.x; acc0.y += v.y; acc0.z += v.z; acc0.w += v.w;
            if (v1) { float4 t = ((const float4*)hrel)[(size_t)n1 * QPR + q];
                      acc1.x += t.x; acc1.y += t.y; acc1.z += t.z; acc1.w += t.w; }
            if (v2) { float4 t = ((const float4*)hrel)[(size_t)n2 * QPR + q];
                      acc2.x += t.x; acc2.y += t.y; acc2.z += t.z; acc2.w += t.w; }
            if (v3) { float4 t = ((const float4*)hrel)[(size_t)n3 * QPR + q];
                      acc3.x += t.x; acc3.y += t.y; acc3.z += t.z; acc3.w += t.w; }
        }
#pragma unroll
        for (int cb = 0; cb < CI / 4; cb++) {
            const float* wr = &s_root[(cb * 4) * CO + c0];
            float4 w0 = *(const float4*)(wr);
            float4 w1 = *(const float4*)(wr + CO);
            float4 w2 = *(const float4*)(wr + 2 * CO);
            float4 w3 = *(const float4*)(wr + 3 * CO);
            float4 e0, e1, e2, e3;
            if (HAS_REL) {
                const float* we = &s_rel[(cb * 4) * CO + c0];
                e0 = *(const float4*)(we);
                e1 = *(const float4*)(we + CO);
                e2 = *(const float4*)(we + 2 * CO);
                e3 = *(const float4*)(we + 3 * CO);
            }
#define LIN_BODY(nk, acck, vk)                                                                        \
            if (vk) {                                                                                 \
                float f0, f1, f2, f3;                                                                 \
                if (IN_BF16) {                                                                        \
                    ushort4 v = *(const ushort4*)((const unsigned short*)hroot_v + (size_t)(nk) * CI + cb * 4); \
                    f0 = bf2f(v.x); f1 = bf2f(v.y); f2 = bf2f(v.z); f3 = bf2f(v.w);                   \
                } else {                                                                              \
                    float4 v = *(const float4*)((const float*)hroot_v + (size_t)(nk) * CI + cb * 4);  \
                    f0 = v.x; f1 = v.y; f2 = v.z; f3 = v.w;                                           \
                }                                                                                     \
                acck.x += f0 * w0.x + f1 * w1.x + f2 * w2.x + f3 * w3.x;                              \
                acck.y += f0 * w0.y + f1 * w1.y + f2 * w2.y + f3 * w3.y;                              \
                acck.z += f0 * w0.z + f1 * w1.z + f2 * w2.z + f3 * w3.z;                              \
                acck.w += f0 * w0.w + f1 * w1.w + f2 * w2.w + f3 * w3.w;                              \
                if (HAS_REL) {                                                                        \
                    float4 a = *(const float4*)(hrel + (size_t)(nk) * CI + cb * 4);                   \
                    acck.x += a.x * e0.x + a.y * e1.x + a.z * e2.x + a.w * e3.x;                      \
                    acck.y += a.x * e0.y + a.y * e1.y + a.z * e2.y + a.w * e3.y;                      \
                    acck.z += a.x * e0.z + a.y * e1.z + a.z * e2.z + a.w * e3.z;                      \
                    acck.w += a.x * e0.w + a.y * e1.w + a.z * e2.w + a.w * e3.w;                      \
                }                                                                                     \
            }
            LIN_BODY(n0, acc0, true)
            LIN_BODY(n1, acc1, v1)
            LIN_BODY(n2, acc2, v2)
            LIN_BODY(n3, acc3, v3)
#undef LIN_BODY
        }
        {
            ((float4*)out)[(size_t)n0 * QPR + q] = acc0;
            s0 += acc0.x; q0 += acc0.x * acc0.x; s1 += acc0.y; q1 += acc0.y * acc0.y;
            s2 += acc0.z; q2 += acc0.z * acc0.z; s3 += acc0.w; q3 += acc0.w * acc0.w;
        }
        if (v1) {
            ((float4*)out)[(size_t)n1 * QPR + q] = acc1;
            s0 += acc1.x; q0 += acc1.x * acc1.x; s1 += acc1.y; q1 += acc1.y * acc1.y;
            s2 += acc1.z; q2 += acc1.z * acc1.z; s3 += acc1.w; q3 += acc1.w * acc1.w;
        }
        if (v2) {
            ((float4*)out)[(size_t)n2 * QPR + q] = acc2;
            s0 += acc2.x; q0 += acc2.x * acc2.x; s1 += acc2.y; q1 += acc2.y * acc2.y;
            s2 += acc2.z; q2 += acc2.z * acc2.z; s3 += acc2.w; q3 += acc2.w * acc2.w;
        }
        if (v3) {
            ((float4*)out)[(size_t)n3 * QPR + q] = acc3;
            s0 += acc3.x; q0 += acc3.x * acc3.x; s1 += acc3.y; q1 += acc3.y * acc3.y;
            s2 += acc3.z; q2 += acc3.z * acc3.z; s3 += acc3.w; q3 += acc3.w * acc3.w;
        }
    }
#pragma unroll
    for (int off = QPR; off < 64; off <<= 1) {
        s0 += __shfl_xor(s0, off, 64); q0 += __shfl_xor(q0, off, 64);
        s1 += __shfl_xor(s1, off, 64); q1 += __shfl_xor(q1, off, 64);
        s2 += __shfl_xor(s2, off, 64); q2 += __shfl_xor(q2, off, 64);
        s3 += __shfl_xor(s3, off, 64); q3 += __shfl_xor(q3, off, 64);
    }
    int lane = tid & 63;
    int w = tid >> 6;
    if (lane < QPR) {
        int cq = lane * 4;
        part[w][cq + 0] = s0; part[w][CO + cq + 0] = q0;
        part[w][cq + 1] = s1; part[w][CO + cq + 1] = q1;
        part[w][cq + 2] = s2; part[w][CO + cq + 2] = q2;
        part[w][cq + 3] = s3; part[w][CO + cq + 3] = q3;
    }
    __syncthreads();
    if (tid < 2 * CO) {
        float v = part[0][tid] + part[1][tid] + part[2][tid] + part[3][tid];
        atomicAdd(&gsl[tid], v);  // 128 addresses; ordering to consumer = next kernel boundary
    }
}

// ---------------- BN apply + ELU: scale/shift from finished gs sums; write bf16 (layers 1-3) ----------------
template <int CO>
__global__ __launch_bounds__(256) void k_bn_elu(const float* __restrict__ h, const float* __restrict__ gsl,
                                                const float* __restrict__ g, const float* __restrict__ be,
                                                unsigned short* __restrict__ hb, float invN, int N) {
    __shared__ float sc[CO], sh[CO];
    if (threadIdx.x < CO) {
        int c = threadIdx.x;
        float mean = gsl[c] * invN;
        float var = gsl[CO + c] * invN - mean * mean;
        float s = g[c] * rsqrtf(var + 1e-5f);
        sc[c] = s;
        sh[c] = be[c] - mean * s;
    }
    __syncthreads();
    int total = N * (CO / 4);
    int i = blockIdx.x * 256 + threadIdx.x;
    if (i >= total) return;
    float4 v = ((const float4*)h)[i];
    int cq = (i % (CO / 4)) * 4;
    v.x = v.x * sc[cq + 0] + sh[cq + 0];
    v.y = v.y * sc[cq + 1] + sh[cq + 1];
    v.z = v.z * sc[cq + 2] + sh[cq + 2];
    v.w = v.w * sc[cq + 3] + sh[cq + 3];
    v.x = v.x > 0.f ? v.x : expm1f(v.x);
    v.y = v.y > 0.f ? v.y : expm1f(v.y);
    v.z = v.z > 0.f ? v.z : expm1f(v.z);
    v.w = v.w > 0.f ? v.w : expm1f(v.w);
    ushort4 o;
    o.x = f2bf(v.x); o.y = f2bf(v.y); o.z = f2bf(v.z); o.w = f2bf(v.w);
    ((ushort4*)hb)[i] = o;
}

// ---------------- layer 4: BN + ELU + global mean pool fused (16 nodes/wave, fp32, no fences) ----------------
__global__ __launch_bounds__(256) void k_bn_elu_pool(const float* __restrict__ h, const float* __restrict__ gsl,
                                                     const float* __restrict__ g, const float* __restrict__ be,
                                                     const int* __restrict__ batch,
                                                     float* __restrict__ pooled, float* __restrict__ cntg,
                                                     float invN, int N) {
    __shared__ float sc[64], sh[64];
    if (threadIdx.x < 64) {
        int c = threadIdx.x;
        float mean = gsl[c] * invN;
        float var = gsl[64 + c] * invN - mean * mean;
        float s = g[c] * rsqrtf(var + 1e-5f);
        sc[c] = s;
        sh[c] = be[c] - mean * s;
    }
    __syncthreads();
    int lane = threadIdx.x & 63;  // lane == channel
    int wid = blockIdx.x * 4 + (threadIdx.x >> 6);
    int n0 = wid * 16;
    if (n0 >= N) return;
    float scl = sc[lane];
    float shl = sh[lane];
    int nmax = N - n0; if (nmax > 16) nmax = 16;
    int cur = batch[n0];
    float acc = 0.f;
    float run = 0.f;
    for (int k = 0; k < nmax; k++) {
        int gg = batch[n0 + k];
        if (gg != cur) {
            atomicAdd(&pooled[(size_t)cur * 64 + lane], acc);
            if (lane == 0) atomicAdd(&cntg[cur], run);
            cur = gg; acc = 0.f; run = 0.f;
        }
        float v = h[(size_t)(n0 + k) * 64 + lane] * scl + shl;
        v = v > 0.f ? v : expm1f(v);
        acc += v;
        run += 1.f;
    }
    atomicAdd(&pooled[(size_t)cur * 64 + lane], acc);
    if (lane == 0) atomicAdd(&cntg[cur], run);
}

// ---------------- head ----------------
__global__ __launch_bounds__(256) void k_head(const float* __restrict__ pooled, const float* __restrict__ cntg,
                                              const float* __restrict__ w1, const float* __restrict__ b1,
                                              const float* __restrict__ w2, const float* __restrict__ b2,
                                              float* __restrict__ out) {
    int g = threadIdx.x;  // 256 threads == 256 graphs
    float rec = 1.0f / fmaxf(cntg[g], 1.0f);
    float p[64];
    {
        const float4* pp = (const float4*)(pooled + (size_t)g * 64);
#pragma unroll
        for (int i = 0; i < 16; i++) {
            float4 v = pp[i];
            p[4 * i + 0] = v.x * rec; p[4 * i + 1] = v.y * rec;
            p[4 * i + 2] = v.z * rec; p[4 * i + 3] = v.w * rec;
        }
    }
    float lg[10];
#pragma unroll
    for (int t = 0; t < 10; t++) lg[t] = b2[t];
#pragma unroll 1
    for (int j = 0; j < 64; j++) {
        float a = b1[j];
#pragma unroll
        for (int k = 0; k < 64; k++) a += p[k] * w1[k * 64 + j];  // uniform -> s_load
        a = fmaxf(a, 0.f);
#pragma unroll
        for (int t = 0; t < 10; t++) lg[t] += a * w2[j * 10 + t];
    }
    float m = -1e30f;
#pragma unroll
    for (int t = 0; t < 10; t++) m = fmaxf(m, lg[t]);
    float s = 0.f;
#pragma unroll
    for (int t = 0; t < 10; t++) s += expf(lg[t] - m);
    float lse = m + logf(s);
#pragma unroll
    for (int t = 0; t < 10; t++) out[(size_t)g * 10 + t] = lg[t] - lse;
}

extern "C" void kernel_launch(void* const* d_in, const int* in_sizes, int n_in,
                              void* d_out, int out_size, void* d_ws, size_t ws_size,
                              hipStream_t stream) {
    const float* x = (const float*)d_in[0];
    const int* ei = (const int*)d_in[1];
    const int* batch = (const int*)d_in[2];
    const int N = in_sizes[0] / 64;
    const int E = in_sizes[1] / 2;
    const int* src = ei;
    const int* dst = ei + E;

    const float* w_rel1 = (const float*)d_in[3];
    const float* w_root1 = (const float*)d_in[4];
    const float* b1 = (const float*)d_in[5];
    const float* g1 = (const float*)d_in[6];
    const float* be1 = (const float*)d_in[7];
    const float* w_rel2 = (const float*)d_in[8];
    const float* w_root2 = (const float*)d_in[9];
    const float* b2 = (const float*)d_in[10];
    const float* g2 = (const float*)d_in[11];
    const float* be2 = (const float*)d_in[12];
    const float* w_rel3 = (const float*)d_in[13];
    const float* w_root3 = (const float*)d_in[14];
    const float* b3 = (const float*)d_in[15];
    const float* g3 = (const float*)d_in[16];
    const float* be3 = (const float*)d_in[17];
    const float* w_rel4 = (const float*)d_in[18];
    const float* w_root4 = (const float*)d_in[19];
    const float* b4 = (const float*)d_in[20];
    const float* g4 = (const float*)d_in[21];
    const float* be4 = (const float*)d_in[22];
    const float* w_lin1 = (const float*)d_in[23];
    const float* b_lin1 = (const float*)d_in[24];
    const float* w_lin2 = (const float*)d_in[25];
    const float* b_lin2 = (const float*)d_in[26];

    char* ws = (char*)d_ws;
    size_t off = 0;
    auto alloc = [&](size_t bytes) { size_t o = off; off += (bytes + 255) & ~(size_t)255; return o; };
    int* hmat = (int*)(ws + alloc((size_t)NSORT * NBUCK * 4));
    int* bstart = (int*)(ws + alloc((size_t)(NBUCK + 1) * 4));
    unsigned* ebuf = (unsigned*)(ws + alloc((size_t)E * 4));
    int* csr = (int*)(ws + alloc((size_t)E * 4));
    int* row_start = (int*)(ws + alloc((size_t)(N + 1) * 4));
    float* agg = (float*)(ws + alloc((size_t)N * 32 * 4));
    unsigned short* y1b = (unsigned short*)(ws + alloc((size_t)N * 16 * 2));
    unsigned short* hb = (unsigned short*)(ws + alloc((size_t)N * 64 * 2));
    float* bufA = (float*)(ws + alloc((size_t)N * 64 * 4));
    // zero region: colpos[512] + gs (4 layers x 128) + pooled + cntg, contiguous
    const int zwords = NBUCK + 512 + NGRAPHS * 64 + NGRAPHS;
    int* colpos = (int*)(ws + alloc((size_t)zwords * 4));
    float* gs = (float*)(colpos + NBUCK);
    float* pooled = gs + 512;
    float* cntg = pooled + NGRAPHS * 64;

    hipMemsetAsync(colpos, 0, (size_t)zwords * 4, stream);

    const float invN = 1.0f / (float)N;
    const int gbl = (N + 3) / 4;       // gather: 4 waves/block, 1 wave/node
    const int nq = (N + 3) / 4;        // lin_stats: nodes per stream
    auto lsgrid = [&](int qpr) { return (nq * qpr + 255) / 256; };

    // ---- CSR build (3 kernels; atomic base claim replaces the serial column scan) ----
    k_bhist<<<1024, 256, 0, stream>>>(dst, hmat, E, x, w_rel1, y1b, colpos, N);
    k_bscatter<<<NSORT, 512, 0, stream>>>(src, dst, hmat, colpos, bstart, ebuf, E);
    k_sort2<<<NBUCK, 256, 0, stream>>>(ebuf, bstart, csr, row_start, N);

    // ---- Layer 1 (64 -> 16) ----
    k_gather<16><<<gbl, 256, 0, stream>>>(y1b, row_start, csr, agg, N);
    k_lin_stats<64, 16, false, true, false><<<lsgrid(4), 256, 0, stream>>>(
        x, agg, nullptr, w_root1, b1, bufA, gs + 0, N);
    k_bn_elu<16><<<(N * 4 + 255) / 256, 256, 0, stream>>>(bufA, gs + 0, g1, be1, hb, invN, N);

    // ---- Layer 2 (16 -> 32) ----
    k_gather<16><<<gbl, 256, 0, stream>>>(hb, row_start, csr, agg, N);
    k_lin_stats<16, 32, true, false, true><<<lsgrid(8), 256, 0, stream>>>(
        hb, agg, w_rel2, w_root2, b2, bufA, gs + 128, N);
    k_bn_elu<32><<<(N * 8 + 255) / 256, 256, 0, stream>>>(bufA, gs + 128, g2, be2, hb, invN, N);

    // ---- Layer 3 (32 -> 32) ----
    k_gather<32><<<gbl, 256, 0, stream>>>(hb, row_start, csr, agg, N);
    k_lin_stats<32, 32, true, false, true><<<lsgrid(8), 256, 0, stream>>>(
        hb, agg, w_rel3, w_root3, b3, bufA, gs + 256, N);
    k_bn_elu<32><<<(N * 8 + 255) / 256, 256, 0, stream>>>(bufA, gs + 256, g3, be3, hb, invN, N);

    // ---- Layer 4 (32 -> 64): lin+stats, then fused BN+ELU+pool ----
    k_gather<32><<<gbl, 256, 0, stream>>>(hb, row_start, csr, agg, N);
    k_lin_stats<32, 64, true, false, true><<<lsgrid(16), 256, 0, stream>>>(
        hb, agg, w_rel4, w_root4, b4, bufA, gs + 384, N);
    int waves16 = (N + 15) / 16;
    k_bn_elu_pool<<<(waves16 + 3) / 4, 256, 0, stream>>>(
        bufA, gs + 384, g4, be4, batch, pooled, cntg, invN, N);

    // ---- head ----
    k_head<<<1, 256, 0, stream>>>(pooled, cntg, w_lin1, b_lin1, w_lin2, b_lin2, (float*)d_out);
}

// Round 9
// 589.522 us; speedup vs baseline: 1.1145x; 1.0336x over previous
//
#include <hip/hip_runtime.h>
#include <hip/hip_bf16.h>
#include <math.h>

#define NGRAPHS 256
#define BSHIFT 8
#define NBUCK 512    // 256-node buckets; covers N up to 131072
#define NSORT 256    // chunks for bhist/bscatter
#define LSTAT 1024   // lin_stats blocks (grid-stride)
#define GCHUNK 1024
#define SMASK 0x00FFFFFFu  // low 24 bits = src (N < 2^24)

__device__ __forceinline__ float bf2f(unsigned short u) {
    return __uint_as_float((unsigned)u << 16);
}
__device__ __forceinline__ unsigned short f2bf(float f) {
    unsigned u = __float_as_uint(f);
    unsigned r = (u + 0x7FFFu + ((u >> 16) & 1u)) >> 16;  // RNE
    return (unsigned short)r;
}

// ---------------- dispatch 1: bucket histogram + atomic base claim (blocks 0..255) || L1 rel matmul (256+) ------
// Each hist block claims its within-bucket base via atomicAdd(colpos) — row order within a bucket is arbitrary,
// which is fine: bucket contents are re-sorted by k_sort2. Kills the serial column-scan dispatch entirely.
__global__ __launch_bounds__(256) void k_bhist(const int* __restrict__ dst, int* __restrict__ hmat, int E,
                                               const float* __restrict__ x, const float* __restrict__ w_rel1,
                                               unsigned short* __restrict__ y1b,
                                               int* __restrict__ colpos, int N) {
    int bid = blockIdx.x, tid = threadIdx.x;
    if (bid < NSORT) {
        __shared__ int hist[NBUCK];
        for (int i = tid; i < NBUCK; i += 256) hist[i] = 0;
        __syncthreads();
        int chunk = (E + NSORT - 1) / NSORT;
        int lo = bid * chunk;
        int hi = lo + chunk; if (hi > E) hi = E;
        for (int i = lo + tid; i < hi; i += 256)
            atomicAdd(&hist[__builtin_nontemporal_load(dst + i) >> BSHIFT], 1);
        __syncthreads();
        for (int i = tid; i < NBUCK; i += 256) {
            int h = hist[i];
            int base = atomicAdd(&colpos[i], h);  // claim [base, base+h) within bucket i
            hmat[(size_t)bid * NBUCK + i] = base;
        }
    } else {
        __shared__ float s_rel[64 * 16];
        for (int i = tid; i < 64 * 16; i += 256) s_rel[i] = w_rel1[i];
        __syncthreads();
        int total = N * 4;
        int nb = gridDim.x - NSORT;
        for (int i = (bid - NSORT) * 256 + tid; i < total; i += nb * 256) {
            int n = i >> 2, c0 = (i & 3) << 2;
            const float4* mp = (const float4*)(x + (size_t)n * 64);
            float4 acc; acc.x = 0.f; acc.y = 0.f; acc.z = 0.f; acc.w = 0.f;
#pragma unroll
            for (int k2 = 0; k2 < 16; k2++) {
                float4 v = mp[k2];
                const float* wr = &s_rel[(k2 * 4) * 16 + c0];
                float4 w0 = *(const float4*)(wr);
                float4 w1 = *(const float4*)(wr + 16);
                float4 w2 = *(const float4*)(wr + 32);
                float4 w3 = *(const float4*)(wr + 48);
                acc.x += v.x * w0.x + v.y * w1.x + v.z * w2.x + v.w * w3.x;
                acc.y += v.x * w0.y + v.y * w1.y + v.z * w2.y + v.w * w3.y;
                acc.z += v.x * w0.z + v.y * w1.z + v.z * w2.z + v.w * w3.z;
                acc.w += v.x * w0.w + v.y * w1.w + v.z * w2.w + v.w * w3.w;
            }
            ushort4 o; o.x = f2bf(acc.x); o.y = f2bf(acc.y); o.z = f2bf(acc.z); o.w = f2bf(acc.w);
            *(ushort4*)(y1b + (size_t)n * 16 + c0) = o;
        }
    }
}

// ---------------- dispatch 2: scatter into bucket-ordered ebuf; per-block redundant 512-entry bucket scan -------
__global__ __launch_bounds__(512) void k_bscatter(const int* __restrict__ src, const int* __restrict__ dst,
                                                  const int* __restrict__ hmat, const int* __restrict__ colpos,
                                                  int* __restrict__ bstart_g,
                                                  unsigned* __restrict__ ebuf, int E) {
    __shared__ int s[NBUCK];
    __shared__ int cur[NBUCK];
    int tid = threadIdx.x;
    int b = blockIdx.x;
    int v = colpos[tid];  // total count of bucket tid (post-bhist)
    s[tid] = v;
    __syncthreads();
    for (int off = 1; off < NBUCK; off <<= 1) {
        int t = (tid >= off) ? s[tid - off] : 0;
        __syncthreads();
        s[tid] += t;
        __syncthreads();
    }
    int excl = s[tid] - v;  // exclusive bucket start
    if (b == 0) {  // publish for k_sort2
        bstart_g[tid] = excl;
        if (tid == NBUCK - 1) bstart_g[NBUCK] = s[NBUCK - 1];
    }
    cur[tid] = excl + hmat[(size_t)b * NBUCK + tid];
    __syncthreads();
    int chunk = (E + NSORT - 1) / NSORT;
    int lo = b * chunk;
    int hi = lo + chunk; if (hi > E) hi = E;
    for (int i = lo + tid; i < hi; i += 512) {
        int d = __builtin_nontemporal_load(dst + i);
        int sv = __builtin_nontemporal_load(src + i);
        int p = atomicAdd(&cur[d >> BSHIFT], 1);
        ebuf[p] = (unsigned)sv | ((unsigned)(d & 255) << 24);
    }
}

// ---------------- dispatch 3: per-bucket LDS counting sort -> full CSR + row_start ----------------
__global__ __launch_bounds__(256) void k_sort2(const unsigned* __restrict__ ebuf, const int* __restrict__ bstart,
                                               int* __restrict__ csr, int* __restrict__ row_start, int N) {
    __shared__ int hist[256];
    __shared__ int sc[256];
    __shared__ int scur[256];
    int b = blockIdx.x;
    int e0 = bstart[b], e1 = bstart[b + 1];
    hist[threadIdx.x] = 0;
    __syncthreads();
    for (int i = e0 + threadIdx.x; i < e1; i += 256)
        atomicAdd(&hist[__builtin_nontemporal_load(ebuf + i) >> 24], 1);
    __syncthreads();
    sc[threadIdx.x] = hist[threadIdx.x];
    __syncthreads();
    for (int off = 1; off < 256; off <<= 1) {
        int t = (threadIdx.x >= off) ? sc[threadIdx.x - off] : 0;
        __syncthreads();
        sc[threadIdx.x] += t;
        __syncthreads();
    }
    {
        int inc = sc[threadIdx.x];
        int ex = inc - hist[threadIdx.x];
        scur[threadIdx.x] = e0 + ex;
        int node = (b << BSHIFT) + threadIdx.x;
        if (node < N) row_start[node] = e0 + ex;
        if (node == N - 1) row_start[N] = e0 + inc;  // == E
    }
    __syncthreads();
    for (int i = e0 + threadIdx.x; i < e1; i += 256) {
        unsigned w = __builtin_nontemporal_load(ebuf + i);
        int p = atomicAdd(&scur[w >> 24], 1);
        csr[p] = (int)(w & SMASK);
    }
}

// ---------------- gather: LDS-staged csr + fully-predicated clamp batches (4 loads in flight) ----------------
template <int C>
__global__ __launch_bounds__(256) void k_gather(const unsigned short* __restrict__ h,
                                                const int* __restrict__ row_start,
                                                const int* __restrict__ csr, float* __restrict__ agg, int N) {
    constexpr int LPR = C / 4;       // lanes per edge-line
    constexpr int EPP = 64 / LPR;    // edge slots per wave instruction
    constexpr int BATCH = 4 * EPP;   // 4 loads in flight per batch
    __shared__ int sbuf[GCHUNK];
    int lane = threadIdx.x & 63;
    int w = threadIdx.x >> 6;
    int nb = blockIdx.x * 4;
    int wid = nb + w;
    bool act = wid < N;
    int nb_end = nb + 4; if (nb_end > N) nb_end = N;
    int eb0 = row_start[nb];
    int eb1 = row_start[nb_end];
    int r0 = act ? row_start[wid] : 0;
    int r1 = act ? row_start[wid + 1] : 0;
    int es = lane / LPR;
    int cq = (lane % LPR) * 4;

    float a0 = 0.f, a1 = 0.f, a2 = 0.f, a3 = 0.f;
    for (int base = eb0; base < eb1; base += GCHUNK) {
        int len = eb1 - base; if (len > GCHUNK) len = GCHUNK;
        __syncthreads();
        for (int i = threadIdx.x; i < len; i += 256)
            sbuf[i] = __builtin_nontemporal_load(csr + base + i);
        __syncthreads();
        if (act) {
            int lo = (r0 > base ? r0 : base) - base;
            int hiv = r1 < base + len ? r1 : base + len;
            int hi = hiv - base;
            for (int j0 = lo; j0 < hi; j0 += BATCH) {
                int s[4]; bool p[4];
#pragma unroll
                for (int u = 0; u < 4; u++) {
                    int j = j0 + u * EPP + es;
                    p[u] = j < hi;
                    s[u] = sbuf[p[u] ? j : j0];  // clamp to batch base: duplicated hot line, no serial path
                }
                ushort4 v[4];
#pragma unroll
                for (int u = 0; u < 4; u++)
                    v[u] = *(const ushort4*)(h + (size_t)s[u] * C + cq);
#pragma unroll
                for (int u = 0; u < 4; u++) {
                    if (p[u]) {
                        a0 += bf2f(v[u].x); a1 += bf2f(v[u].y);
                        a2 += bf2f(v[u].z); a3 += bf2f(v[u].w);
                    }
                }
            }
        }
    }
#pragma unroll
    for (int off = LPR; off < 64; off <<= 1) {
        a0 += __shfl_xor(a0, off, 64);
        a1 += __shfl_xor(a1, off, 64);
        a2 += __shfl_xor(a2, off, 64);
        a3 += __shfl_xor(a3, off, 64);
    }
    if (act && lane < LPR) {
        int deg = r1 - r0;
        float rec = 1.0f / (float)(deg > 0 ? deg : 1);
        float4 o; o.x = a0 * rec; o.y = a1 * rec; o.z = a2 * rec; o.w = a3 * rec;
        *(float4*)(agg + (size_t)wid * C + cq) = o;
    }
}

// ---------------- dense layer + BN-stat sums (round-6 proven form: 1 elem/thread, grid-stride) ----------------
template <int CI, int CO, bool HAS_REL, bool ADD_AGG, bool IN_BF16>
__global__ __launch_bounds__(256) void k_lin_stats(const void* __restrict__ hroot_v, const float* __restrict__ hrel,
                                                   const float* __restrict__ w_rel, const float* __restrict__ w_root,
                                                   const float* __restrict__ bias,
                                                   float* __restrict__ out, float* __restrict__ gsl, int N) {
    constexpr int QPR = CO / 4;
    __shared__ float s_rel[HAS_REL ? CI * CO : 1];
    __shared__ float s_root[CI * CO];
    __shared__ float s_b[CO];
    __shared__ float part[4][2 * CO];
    int tid = threadIdx.x;
    if (HAS_REL)
        for (int i = tid; i < CI * CO; i += 256) s_rel[i] = w_rel[i];
    for (int i = tid; i < CI * CO; i += 256) s_root[i] = w_root[i];
    if (tid < CO) s_b[tid] = bias[tid];
    __syncthreads();

    int total = N * QPR;
    int stride = gridDim.x * 256;  // multiple of QPR -> c0 constant per thread
    float s0 = 0, s1 = 0, s2 = 0, s3 = 0, q0 = 0, q1 = 0, q2 = 0, q3 = 0;
    for (int i = blockIdx.x * 256 + tid; i < total; i += stride) {
        int n = i / QPR, c0 = (i % QPR) * 4;
        float4 acc = *(const float4*)&s_b[c0];
        if (ADD_AGG) {
            float4 v = ((const float4*)hrel)[i];
            acc.x += v.x; acc.y += v.y; acc.z += v.z; acc.w += v.w;
        }
#pragma unroll
        for (int cb = 0; cb < CI / 4; cb++) {
            float f0, f1, f2, f3;
            if (IN_BF16) {
                ushort4 v = *(const ushort4*)((const unsigned short*)hroot_v + (size_t)n * CI + cb * 4);
                f0 = bf2f(v.x); f1 = bf2f(v.y); f2 = bf2f(v.z); f3 = bf2f(v.w);
            } else {
                float4 v = *(const float4*)((const float*)hroot_v + (size_t)n * CI + cb * 4);
                f0 = v.x; f1 = v.y; f2 = v.z; f3 = v.w;
            }
            const float* wr = &s_root[(cb * 4) * CO + c0];
            float4 w0 = *(const float4*)(wr);
            float4 w1 = *(const float4*)(wr + CO);
            float4 w2 = *(const float4*)(wr + 2 * CO);
            float4 w3 = *(const float4*)(wr + 3 * CO);
            acc.x += f0 * w0.x + f1 * w1.x + f2 * w2.x + f3 * w3.x;
            acc.y += f0 * w0.y + f1 * w1.y + f2 * w2.y + f3 * w3.y;
            acc.z += f0 * w0.z + f1 * w1.z + f2 * w2.z + f3 * w3.z;
            acc.w += f0 * w0.w + f1 * w1.w + f2 * w2.w + f3 * w3.w;
            if (HAS_REL) {
                float4 a = *(const float4*)(hrel + (size_t)n * CI + cb * 4);
                const float* we = &s_rel[(cb * 4) * CO + c0];
                float4 e0 = *(const float4*)(we);
                float4 e1 = *(const float4*)(we + CO);
                float4 e2 = *(const float4*)(we + 2 * CO);
                float4 e3 = *(const float4*)(we + 3 * CO);
                acc.x += a.x * e0.x + a.y * e1.x + a.z * e2.x + a.w * e3.x;
                acc.y += a.x * e0.y + a.y * e1.y + a.z * e2.y + a.w * e3.y;
                acc.z += a.x * e0.z + a.y * e1.z + a.z * e2.z + a.w * e3.z;
                acc.w += a.x * e0.w + a.y * e1.w + a.z * e2.w + a.w * e3.w;
            }
        }
        ((float4*)out)[i] = acc;
        s0 += acc.x; q0 += acc.x * acc.x;
        s1 += acc.y; q1 += acc.y * acc.y;
        s2 += acc.z; q2 += acc.z * acc.z;
        s3 += acc.w; q3 += acc.w * acc.w;
    }
#pragma unroll
    for (int off = QPR; off < 64; off <<= 1) {
        s0 += __shfl_xor(s0, off, 64); q0 += __shfl_xor(q0, off, 64);
        s1 += __shfl_xor(s1, off, 64); q1 += __shfl_xor(q1, off, 64);
        s2 += __shfl_xor(s2, off, 64); q2 += __shfl_xor(q2, off, 64);
        s3 += __shfl_xor(s3, off, 64); q3 += __shfl_xor(q3, off, 64);
    }
    int lane = tid & 63;
    int w = tid >> 6;
    if (lane < QPR) {
        int cq = lane * 4;
        part[w][cq + 0] = s0; part[w][CO + cq + 0] = q0;
        part[w][cq + 1] = s1; part[w][CO + cq + 1] = q1;
        part[w][cq + 2] = s2; part[w][CO + cq + 2] = q2;
        part[w][cq + 3] = s3; part[w][CO + cq + 3] = q3;
    }
    __syncthreads();
    if (tid < 2 * CO) {
        float v = part[0][tid] + part[1][tid] + part[2][tid] + part[3][tid];
        atomicAdd(&gsl[tid], v);  // 128 addresses; ordering to consumer = next kernel boundary
    }
}

// ---------------- BN apply + ELU: scale/shift from finished gs sums; write bf16 (layers 1-3) ----------------
template <int CO>
__global__ __launch_bounds__(256) void k_bn_elu(const float* __restrict__ h, const float* __restrict__ gsl,
                                                const float* __restrict__ g, const float* __restrict__ be,
                                                unsigned short* __restrict__ hb, float invN, int N) {
    __shared__ float sc[CO], sh[CO];
    if (threadIdx.x < CO) {
        int c = threadIdx.x;
        float mean = gsl[c] * invN;
        float var = gsl[CO + c] * invN - mean * mean;
        float s = g[c] * rsqrtf(var + 1e-5f);
        sc[c] = s;
        sh[c] = be[c] - mean * s;
    }
    __syncthreads();
    int total = N * (CO / 4);
    int i = blockIdx.x * 256 + threadIdx.x;
    if (i >= total) return;
    float4 v = ((const float4*)h)[i];
    int cq = (i % (CO / 4)) * 4;
    v.x = v.x * sc[cq + 0] + sh[cq + 0];
    v.y = v.y * sc[cq + 1] + sh[cq + 1];
    v.z = v.z * sc[cq + 2] + sh[cq + 2];
    v.w = v.w * sc[cq + 3] + sh[cq + 3];
    v.x = v.x > 0.f ? v.x : expm1f(v.x);
    v.y = v.y > 0.f ? v.y : expm1f(v.y);
    v.z = v.z > 0.f ? v.z : expm1f(v.z);
    v.w = v.w > 0.f ? v.w : expm1f(v.w);
    ushort4 o;
    o.x = f2bf(v.x); o.y = f2bf(v.y); o.z = f2bf(v.z); o.w = f2bf(v.w);
    ((ushort4*)hb)[i] = o;
}

// ---------------- layer 4: BN + ELU + global mean pool fused (16 nodes/wave, fp32, no fences) ----------------
__global__ __launch_bounds__(256) void k_bn_elu_pool(const float* __restrict__ h, const float* __restrict__ gsl,
                                                     const float* __restrict__ g, const float* __restrict__ be,
                                                     const int* __restrict__ batch,
                                                     float* __restrict__ pooled, float* __restrict__ cntg,
                                                     float invN, int N) {
    __shared__ float sc[64], sh[64];
    if (threadIdx.x < 64) {
        int c = threadIdx.x;
        float mean = gsl[c] * invN;
        float var = gsl[64 + c] * invN - mean * mean;
        float s = g[c] * rsqrtf(var + 1e-5f);
        sc[c] = s;
        sh[c] = be[c] - mean * s;
    }
    __syncthreads();
    int lane = threadIdx.x & 63;  // lane == channel
    int wid = blockIdx.x * 4 + (threadIdx.x >> 6);
    int n0 = wid * 16;
    if (n0 >= N) return;
    float scl = sc[lane];
    float shl = sh[lane];
    int nmax = N - n0; if (nmax > 16) nmax = 16;
    int cur = batch[n0];
    float acc = 0.f;
    float run = 0.f;
    for (int k = 0; k < nmax; k++) {
        int gg = batch[n0 + k];
        if (gg != cur) {
            atomicAdd(&pooled[(size_t)cur * 64 + lane], acc);
            if (lane == 0) atomicAdd(&cntg[cur], run);
            cur = gg; acc = 0.f; run = 0.f;
        }
        float v = h[(size_t)(n0 + k) * 64 + lane] * scl + shl;
        v = v > 0.f ? v : expm1f(v);
        acc += v;
        run += 1.f;
    }
    atomicAdd(&pooled[(size_t)cur * 64 + lane], acc);
    if (lane == 0) atomicAdd(&cntg[cur], run);
}

// ---------------- head ----------------
__global__ __launch_bounds__(256) void k_head(const float* __restrict__ pooled, const float* __restrict__ cntg,
                                              const float* __restrict__ w1, const float* __restrict__ b1,
                                              const float* __restrict__ w2, const float* __restrict__ b2,
                                              float* __restrict__ out) {
    int g = threadIdx.x;  // 256 threads == 256 graphs
    float rec = 1.0f / fmaxf(cntg[g], 1.0f);
    float p[64];
    {
        const float4* pp = (const float4*)(pooled + (size_t)g * 64);
#pragma unroll
        for (int i = 0; i < 16; i++) {
            float4 v = pp[i];
            p[4 * i + 0] = v.x * rec; p[4 * i + 1] = v.y * rec;
            p[4 * i + 2] = v.z * rec; p[4 * i + 3] = v.w * rec;
        }
    }
    float lg[10];
#pragma unroll
    for (int t = 0; t < 10; t++) lg[t] = b2[t];
#pragma unroll 1
    for (int j = 0; j < 64; j++) {
        float a = b1[j];
#pragma unroll
        for (int k = 0; k < 64; k++) a += p[k] * w1[k * 64 + j];  // uniform -> s_load
        a = fmaxf(a, 0.f);
#pragma unroll
        for (int t = 0; t < 10; t++) lg[t] += a * w2[j * 10 + t];
    }
    float m = -1e30f;
#pragma unroll
    for (int t = 0; t < 10; t++) m = fmaxf(m, lg[t]);
    float s = 0.f;
#pragma unroll
    for (int t = 0; t < 10; t++) s += expf(lg[t] - m);
    float lse = m + logf(s);
#pragma unroll
    for (int t = 0; t < 10; t++) out[(size_t)g * 10 + t] = lg[t] - lse;
}

extern "C" void kernel_launch(void* const* d_in, const int* in_sizes, int n_in,
                              void* d_out, int out_size, void* d_ws, size_t ws_size,
                              hipStream_t stream) {
    const float* x = (const float*)d_in[0];
    const int* ei = (const int*)d_in[1];
    const int* batch = (const int*)d_in[2];
    const int N = in_sizes[0] / 64;
    const int E = in_sizes[1] / 2;
    const int* src = ei;
    const int* dst = ei + E;

    const float* w_rel1 = (const float*)d_in[3];
    const float* w_root1 = (const float*)d_in[4];
    const float* b1 = (const float*)d_in[5];
    const float* g1 = (const float*)d_in[6];
    const float* be1 = (const float*)d_in[7];
    const float* w_rel2 = (const float*)d_in[8];
    const float* w_root2 = (const float*)d_in[9];
    const float* b2 = (const float*)d_in[10];
    const float* g2 = (const float*)d_in[11];
    const float* be2 = (const float*)d_in[12];
    const float* w_rel3 = (const float*)d_in[13];
    const float* w_root3 = (const float*)d_in[14];
    const float* b3 = (const float*)d_in[15];
    const float* g3 = (const float*)d_in[16];
    const float* be3 = (const float*)d_in[17];
    const float* w_rel4 = (const float*)d_in[18];
    const float* w_root4 = (const float*)d_in[19];
    const float* b4 = (const float*)d_in[20];
    const float* g4 = (const float*)d_in[21];
    const float* be4 = (const float*)d_in[22];
    const float* w_lin1 = (const float*)d_in[23];
    const float* b_lin1 = (const float*)d_in[24];
    const float* w_lin2 = (const float*)d_in[25];
    const float* b_lin2 = (const float*)d_in[26];

    char* ws = (char*)d_ws;
    size_t off = 0;
    auto alloc = [&](size_t bytes) { size_t o = off; off += (bytes + 255) & ~(size_t)255; return o; };
    int* hmat = (int*)(ws + alloc((size_t)NSORT * NBUCK * 4));
    int* bstart = (int*)(ws + alloc((size_t)(NBUCK + 1) * 4));
    unsigned* ebuf = (unsigned*)(ws + alloc((size_t)E * 4));
    int* csr = (int*)(ws + alloc((size_t)E * 4));
    int* row_start = (int*)(ws + alloc((size_t)(N + 1) * 4));
    float* agg = (float*)(ws + alloc((size_t)N * 32 * 4));
    unsigned short* y1b = (unsigned short*)(ws + alloc((size_t)N * 16 * 2));
    unsigned short* hb = (unsigned short*)(ws + alloc((size_t)N * 64 * 2));
    float* bufA = (float*)(ws + alloc((size_t)N * 64 * 4));
    // zero region: colpos[512] + gs (4 layers x 128) + pooled + cntg, contiguous
    const int zwords = NBUCK + 512 + NGRAPHS * 64 + NGRAPHS;
    int* colpos = (int*)(ws + alloc((size_t)zwords * 4));
    float* gs = (float*)(colpos + NBUCK);
    float* pooled = gs + 512;
    float* cntg = pooled + NGRAPHS * 64;

    hipMemsetAsync(colpos, 0, (size_t)zwords * 4, stream);

    const float invN = 1.0f / (float)N;
    const int gbl = (N + 3) / 4;       // gather: 4 waves/block, 1 wave/node

    // ---- CSR build (3 kernels; atomic base claim replaces the serial column scan) ----
    k_bhist<<<1024, 256, 0, stream>>>(dst, hmat, E, x, w_rel1, y1b, colpos, N);
    k_bscatter<<<NSORT, 512, 0, stream>>>(src, dst, hmat, colpos, bstart, ebuf, E);
    k_sort2<<<NBUCK, 256, 0, stream>>>(ebuf, bstart, csr, row_start, N);

    // ---- Layer 1 (64 -> 16) ----
    k_gather<16><<<gbl, 256, 0, stream>>>(y1b, row_start, csr, agg, N);
    k_lin_stats<64, 16, false, true, false><<<LSTAT, 256, 0, stream>>>(
        x, agg, nullptr, w_root1, b1, bufA, gs + 0, N);
    k_bn_elu<16><<<(N * 4 + 255) / 256, 256, 0, stream>>>(bufA, gs + 0, g1, be1, hb, invN, N);

    // ---- Layer 2 (16 -> 32) ----
    k_gather<16><<<gbl, 256, 0, stream>>>(hb, row_start, csr, agg, N);
    k_lin_stats<16, 32, true, false, true><<<LSTAT, 256, 0, stream>>>(
        hb, agg, w_rel2, w_root2, b2, bufA, gs + 128, N);
    k_bn_elu<32><<<(N * 8 + 255) / 256, 256, 0, stream>>>(bufA, gs + 128, g2, be2, hb, invN, N);

    // ---- Layer 3 (32 -> 32) ----
    k_gather<32><<<gbl, 256, 0, stream>>>(hb, row_start, csr, agg, N);
    k_lin_stats<32, 32, true, false, true><<<LSTAT, 256, 0, stream>>>(
        hb, agg, w_rel3, w_root3, b3, bufA, gs + 256, N);
    k_bn_elu<32><<<(N * 8 + 255) / 256, 256, 0, stream>>>(bufA, gs + 256, g3, be3, hb, invN, N);

    // ---- Layer 4 (32 -> 64): lin+stats, then fused BN+ELU+pool ----
    k_gather<32><<<gbl, 256, 0, stream>>>(hb, row_start, csr, agg, N);
    k_lin_stats<32, 64, true, false, true><<<LSTAT, 256, 0, stream>>>(
        hb, agg, w_rel4, w_root4, b4, bufA, gs + 384, N);
    int waves16 = (N + 15) / 16;
    k_bn_elu_pool<<<(waves16 + 3) / 4, 256, 0, stream>>>(
        bufA, gs + 384, g4, be4, batch, pooled, cntg, invN, N);

    // ---- head ----
    k_head<<<1, 256, 0, stream>>>(pooled, cntg, w_lin1, b_lin1, w_lin2, b_lin2, (float*)d_out);
}